// Round 21
// baseline (8412.260 us; speedup 1.0000x reference)
//
#include <hip/hip_runtime.h>
#include <math.h>

// HeterogeneousGNN fused kernel for MI355X (gfx950) — round 21.
// Base = R19/R20 (632 us). Decode: ~55% stall = 96 cross-wave barriers/block,
// each exposing the Gc LDS round-trip at 2 waves/SIMD. R21: WAVE-PRIVATE Gc.
// Wave w's GEMM2 o-slice = the o-tile its own GEMM1 produced; the 32x32 G
// tile lives in a private 2.25KB LDS buffer (write C/D-layout, read B-frag
// layout -- the LDS does the transpose; 72-B row stride ~2-way banks).
// Wave-local ds ordering needs NO barrier -> GEMM phase has ZERO barriers
// (3/layer remain for cross-wave LN stats). acc[8] = 256u x 32o = 128 AGPR.
// Cost: A-frags read by all 4 waves (x4 L2 traffic; A3=512KB, XCD-resident).

typedef float  f32x4  __attribute__((ext_vector_type(4)));
typedef float  f32x16 __attribute__((ext_vector_type(16)));
typedef short  s16x8  __attribute__((ext_vector_type(8)));
typedef __bf16 bf16x8 __attribute__((ext_vector_type(8)));

#define GOFF 65536   // private-Gc / stats / readout scratch (9216 B)

__device__ __forceinline__ unsigned short f2bf(float f) {
  __bf16 h = (__bf16)f;
  return __builtin_bit_cast(unsigned short, h);
}
__device__ __forceinline__ float bf2f(unsigned short h) {
  return __builtin_bit_cast(float, (unsigned int)h << 16);
}
__device__ __forceinline__ unsigned short f2bf_rne(float f) {
  unsigned int u = __builtin_bit_cast(unsigned int, f);
  u = (u + 0x7fffu + ((u >> 16) & 1u)) >> 16;
  return (unsigned short)u;
}

// exact-GELU via A&S 7.1.26 erf (max abs err 1.5e-7, << bf16 rounding)
__device__ __forceinline__ float gelu_fast(float x) {
  float z = fabsf(x) * 0.70710678f;
  float t = __builtin_amdgcn_rcpf(1.f + 0.3275911f * z);
  float p = t * (0.254829592f + t * (-0.284496736f + t * (1.421413741f +
            t * (-1.453152027f + t * 1.061405429f))));
  float e = __builtin_expf(-z * z);
  float erfv = 1.f - p * e;
  erfv = (x < 0.f) ? -erfv : erfv;
  return 0.5f * x * (1.f + erfv);
}

// H: [256 v][128 d] bf16; XOR (v&15) -> column b128 reads 2-way (free).
__device__ __forceinline__ int haddr(int v, int d) {
  return v * 256 + ((d * 2) ^ ((v & 15) << 4));
}

#define MFMA32(a, b, c) __builtin_amdgcn_mfma_f32_32x32x16_bf16( \
    __builtin_bit_cast(bf16x8, (a)), __builtin_bit_cast(bf16x8, (b)), (c), 0, 0, 0)

// ---- prep: fragment-ordered A3 / W3 (bf16) — unchanged ----
// A3[h][ut 0..7][vt 0..15][lane][j] = Ac_h[u=ut*32+(lane&31)][v=vt*16+(lane>>5)*8+j]
// W3[hw 0..5][ot 0..3][kt 0..7][lane][j] = W_hw[o=ot*32+(lane&31)][d=kt*16+(lane>>5)*8+j]
__global__ void prep_kernel(const float* __restrict__ alp, const float* __restrict__ aln,
                            const float* __restrict__ wp,  const float* __restrict__ wn,
                            unsigned short* __restrict__ A3, unsigned short* __restrict__ W3) {
  int idx = blockIdx.x * 512 + threadIdx.x;     // 229376 threads total
  if (idx < 131072) {
    int j = idx & 7, lane = (idx >> 3) & 63, vt = (idx >> 9) & 15,
        ut = (idx >> 13) & 7, h = (idx >> 16) & 1;
    int u = ut * 32 + (lane & 31);
    int v = vt * 16 + (lane >> 5) * 8 + j;
    int s = u * 256 + v;
    float ap = 1.f / (1.f + expf(-alp[s]));
    float an = 1.f / (1.f + expf(-aln[s]));
    bool  m  = ap > an;
    float val = h ? (m ? 0.f : -an) : (m ? ap : 0.f);   // neg sign folded
    A3[idx] = f2bf_rne(val);
  } else {
    int k = idx - 131072;                       // 0 .. 98303
    int j = k & 7, lane = (k >> 3) & 63, kt = (k >> 9) & 7,
        ot = (k >> 12) & 3, hw = (k >> 14);     // hw = l*2 + (0=pos,1=neg)
    int o = ot * 32 + (lane & 31);
    int d = kt * 16 + (lane >> 5) * 8 + j;
    const float* src = (hw & 1) ? wn : wp;
    W3[k] = f2bf_rne(src[(hw >> 1) * 16384 + o * 128 + d]);
  }
}

__global__ __launch_bounds__(256, 2) void gnn_kernel(
    const float* __restrict__ X,
    const unsigned short* __restrict__ A3,
    const unsigned short* __restrict__ W3,
    const float* __restrict__ ln_g, const float* __restrict__ ln_b,
    const float* __restrict__ ro_g, const float* __restrict__ ro_b,
    float* __restrict__ out) {
  extern __shared__ char smem[];
  const int tid  = threadIdx.x;
  const int wid  = tid >> 6;        // 0..3: o-slice base = wid*32
  const int lane = tid & 63;
  const int l31  = lane & 31;
  const int hi   = lane >> 5;
  const int b    = blockIdx.x;
  const int gp   = GOFF + wid * 2304;   // private Gc_T: [32 o][72 B rows]

  // ---- stage H = bf16(X[b]) into LDS ----
  {
    const float4* Xb = (const float4*)(X + (size_t)b * 256 * 128);
#pragma unroll 8
    for (int i = 0; i < 32; ++i) {
      int idx = tid + i * 256;
      int v = idx >> 5, d = (idx & 31) * 4;
      float4 f = Xb[idx];
      ushort4 p;
      p.x = f2bf(f.x); p.y = f2bf(f.y); p.z = f2bf(f.z); p.w = f2bf(f.w);
      *(ushort4*)(smem + haddr(v, d)) = p;
    }
  }
  __syncthreads();

  for (int l = 0; l < 3; ++l) {
    f32x16 acc[8];                    // 256u x 32o per wave
#pragma unroll
    for (int ut = 0; ut < 8; ++ut)
#pragma unroll
      for (int r = 0; r < 16; ++r) acc[ut][r] = 0.f;

    for (int h = 0; h < 2; ++h) {
      const unsigned short* Wb = W3 + (size_t)(((l * 2 + h) * 4 + wid) * 8) * 512;
      const unsigned short* Ab = A3 + (size_t)h * 65536;

      s16x8 wreg[8];                  // this wave's W o-tile (32 regs)
#pragma unroll
      for (int kt = 0; kt < 8; ++kt)
        wreg[kt] = *(const s16x8*)(Wb + (size_t)kt * 512 + lane * 8);

#pragma unroll 1
      for (int c = 0; c < 8; ++c) {   // v-chunks of 32 nodes; NO barriers
        // ---- GEMM1: g0 = H[c][32v] @ W^T (32x32 tile) ----
        f32x16 g0;
#pragma unroll
        for (int r = 0; r < 16; ++r) g0[r] = 0.f;
        const int v0 = c * 32 + l31;
#pragma unroll
        for (int kt = 0; kt < 8; ++kt) {
          s16x8 ha = *(const s16x8*)(smem + haddr(v0, kt * 16 + hi * 8));
          g0 = MFMA32(ha, wreg[kt], g0);
        }
        // write private Gc_T[o = l31][v]; C/D: reg r -> v=(r&3)+8*(r>>2)+4*hi
#pragma unroll
        for (int rq = 0; rq < 4; ++rq) {
          int vr = rq * 8 + hi * 4;
          ushort4 p;
          p.x = f2bf(g0[rq*4+0]); p.y = f2bf(g0[rq*4+1]);
          p.z = f2bf(g0[rq*4+2]); p.w = f2bf(g0[rq*4+3]);
          *(ushort4*)(smem + gp + l31 * 72 + vr * 2) = p;
        }
        // ---- GEMM2: acc[256u x 32o] += A_h[u, chunk c] @ g (wave-local) ----
#pragma unroll
        for (int kt2 = 0; kt2 < 2; ++kt2) {
          s16x8 bf = *(const s16x8*)(smem + gp + l31 * 72 + (kt2 * 16 + hi * 8) * 2);
#pragma unroll 4
          for (int ut = 0; ut < 8; ++ut) {
            s16x8 a = *(const s16x8*)(Ab + (size_t)(ut * 16 + c * 2 + kt2) * 512 + lane * 8);
            acc[ut] = MFMA32(a, bf, acc[ut]);
          }
        }
      } // chunks
    } // halves  — zero barriers above

    // ---- epilogue: GELU + cross-wave LayerNorm (3 barriers) ----
    const float lgv = ln_g[l * 128 + wid * 32 + l31];
    const float lbv = ln_b[l * 128 + wid * 32 + l31];
    float st1[8], st2[8];
#pragma unroll
    for (int ut = 0; ut < 8; ++ut) {
      st1[ut] = 0.f; st2[ut] = 0.f;
#pragma unroll
      for (int r = 0; r < 16; ++r) {
        float x = gelu_fast(acc[ut][r]);
        acc[ut][r] = x;
        float s1 = x, s2 = x * x;
#pragma unroll
        for (int m = 1; m < 32; m <<= 1) {     // reduce this wave's 32-o slice
          s1 += __shfl_xor(s1, m);
          s2 += __shfl_xor(s2, m);
        }
        if (l31 == r) { st1[ut] = s1; st2[ut] = s2; }
      }
    }
    __syncthreads();                 // bar 1: all GEMM / private-Gc reads done
    if (l31 < 16) {                  // stats[u][wid] float2 in the Gc region
      int rr = (l31 & 3) + 8 * ((l31 >> 2) & 3) + 4 * hi;
#pragma unroll
      for (int ut = 0; ut < 8; ++ut) {
        int u = ut * 32 + rr;
        float2 pw; pw.x = st1[ut]; pw.y = st2[ut];
        *(float2*)(smem + GOFF + u * 32 + wid * 8) = pw;
      }
    }
    __syncthreads();                 // bar 2: stats ready
#pragma unroll 2
    for (int ut = 0; ut < 8; ++ut)
#pragma unroll
      for (int r = 0; r < 16; ++r) {
        int u = ut * 32 + (r & 3) + 8 * ((r >> 2) & 3) + 4 * hi;
        float mu = 0.f, rs = 0.f;
        if (l31 == r) {
          f32x4 sa = *(const f32x4*)(smem + GOFF + u * 32);
          f32x4 sb = *(const f32x4*)(smem + GOFF + u * 32 + 16);
          float s1 = sa[0] + sa[2] + sb[0] + sb[2];
          float s2 = sa[1] + sa[3] + sb[1] + sb[3];
          mu = s1 * (1.f / 128.f);
          float var = s2 * (1.f / 128.f) - mu * mu;
          rs = rsqrtf(var + 1e-5f);
        }
        mu = __shfl(mu, (lane & 32) + r);      // broadcast within half-wave
        rs = __shfl(rs, (lane & 32) + r);
        float y = (acc[ut][r] - mu) * rs * lgv + lbv;
        *(unsigned short*)(smem + haddr(u, wid * 32 + l31)) = f2bf(y);
      }
    __syncthreads();                 // bar 3: H' ready for next layer
  } // layers

  // ---- readout: mean over nodes + final LN ----
  {
    int d   = tid & 127;
    int grp = tid >> 7;
    float s = 0.f;
    for (int v = grp * 128; v < grp * 128 + 128; ++v)
      s += bf2f(*(const unsigned short*)(smem + haddr(v, d)));
    float* red = (float*)(smem + GOFF);
    red[grp * 128 + d] = s;
    __syncthreads();
    if (tid < 128) {
      red[256 + tid] = (red[tid] + red[128 + tid]) * (1.f / 256.f);
    }
    __syncthreads();
    if (tid < 64) {
      float a  = red[256 + tid];
      float b2 = red[256 + 64 + tid];
      float s1 = a + b2, s2 = a * a + b2 * b2;
#pragma unroll
      for (int m = 1; m < 64; m <<= 1) {
        s1 += __shfl_xor(s1, m);
        s2 += __shfl_xor(s2, m);
      }
      float mu  = s1 * (1.f / 128.f);
      float var = s2 * (1.f / 128.f) - mu * mu;
      float rs  = rsqrtf(var + 1e-5f);
      out[(size_t)b * 128 + tid]      = (a  - mu) * rs * ro_g[tid]      + ro_b[tid];
      out[(size_t)b * 128 + 64 + tid] = (b2 - mu) * rs * ro_g[64 + tid] + ro_b[64 + tid];
    }
  }
}

extern "C" void kernel_launch(void* const* d_in, const int* in_sizes, int n_in,
                              void* d_out, int out_size, void* d_ws, size_t ws_size,
                              hipStream_t stream) {
  const float* X   = (const float*)d_in[0];
  const float* alp = (const float*)d_in[1];
  const float* aln = (const float*)d_in[2];
  const float* wp  = (const float*)d_in[3];
  const float* wn  = (const float*)d_in[4];
  const float* lng = (const float*)d_in[5];
  const float* lnb = (const float*)d_in[6];
  const float* rog = (const float*)d_in[7];
  const float* rob = (const float*)d_in[8];
  float* out = (float*)d_out;

  unsigned short* A3 = (unsigned short*)d_ws;          // 131072 bf16 = 256 KB
  unsigned short* W3 = A3 + 131072;                    //  98304 bf16 = 192 KB

  (void)hipFuncSetAttribute(reinterpret_cast<const void*>(gnn_kernel),
                            hipFuncAttributeMaxDynamicSharedMemorySize, 74752);

  prep_kernel<<<448, 512, 0, stream>>>(alp, aln, wp, wn, A3, W3);
  gnn_kernel<<<2048, 256, 74752, stream>>>(X, A3, W3, lng, lnb, rog, rob, out);
}

// Round 22
// 4558.302 us; speedup vs baseline: 1.8455x; 1.8455x over previous
//
#include <hip/hip_runtime.h>
#include <math.h>

// HeterogeneousGNN fused kernel for MI355X (gfx950) — round 22.
// R21 (wave-private Gc, zero GEMM-phase barriers) regressed 13x from a rule
// #20 violation: PARTIAL unrolls (#pragma unroll 4 / 2) on loops indexing
// acc[ut] left runtime indices -> acc allocated in SCRATCH (28 GB writes).
// R22 = R21 with every acc/st-touching loop FULLY unrolled. Structure
// unchanged: wave w's GEMM2 o-slice = its own GEMM1 o-tile via a private
// 2.25 KB LDS buffer (wave-local ds ordering, no barrier); 3 barriers/layer
// (cross-wave LN stats only); acc[8] = 256u x 32o = 128 AGPR.

typedef float  f32x4  __attribute__((ext_vector_type(4)));
typedef float  f32x16 __attribute__((ext_vector_type(16)));
typedef short  s16x8  __attribute__((ext_vector_type(8)));
typedef __bf16 bf16x8 __attribute__((ext_vector_type(8)));

#define GOFF 65536   // private-Gc / stats / readout scratch (9216 B)

__device__ __forceinline__ unsigned short f2bf(float f) {
  __bf16 h = (__bf16)f;
  return __builtin_bit_cast(unsigned short, h);
}
__device__ __forceinline__ float bf2f(unsigned short h) {
  return __builtin_bit_cast(float, (unsigned int)h << 16);
}
__device__ __forceinline__ unsigned short f2bf_rne(float f) {
  unsigned int u = __builtin_bit_cast(unsigned int, f);
  u = (u + 0x7fffu + ((u >> 16) & 1u)) >> 16;
  return (unsigned short)u;
}

// exact-GELU via A&S 7.1.26 erf (max abs err 1.5e-7, << bf16 rounding)
__device__ __forceinline__ float gelu_fast(float x) {
  float z = fabsf(x) * 0.70710678f;
  float t = __builtin_amdgcn_rcpf(1.f + 0.3275911f * z);
  float p = t * (0.254829592f + t * (-0.284496736f + t * (1.421413741f +
            t * (-1.453152027f + t * 1.061405429f))));
  float e = __builtin_expf(-z * z);
  float erfv = 1.f - p * e;
  erfv = (x < 0.f) ? -erfv : erfv;
  return 0.5f * x * (1.f + erfv);
}

// H: [256 v][128 d] bf16; XOR (v&15) -> column b128 reads 2-way (free).
__device__ __forceinline__ int haddr(int v, int d) {
  return v * 256 + ((d * 2) ^ ((v & 15) << 4));
}

#define MFMA32(a, b, c) __builtin_amdgcn_mfma_f32_32x32x16_bf16( \
    __builtin_bit_cast(bf16x8, (a)), __builtin_bit_cast(bf16x8, (b)), (c), 0, 0, 0)

// ---- prep: fragment-ordered A3 / W3 (bf16) — unchanged ----
// A3[h][ut 0..7][vt 0..15][lane][j] = Ac_h[u=ut*32+(lane&31)][v=vt*16+(lane>>5)*8+j]
// W3[hw 0..5][ot 0..3][kt 0..7][lane][j] = W_hw[o=ot*32+(lane&31)][d=kt*16+(lane>>5)*8+j]
__global__ void prep_kernel(const float* __restrict__ alp, const float* __restrict__ aln,
                            const float* __restrict__ wp,  const float* __restrict__ wn,
                            unsigned short* __restrict__ A3, unsigned short* __restrict__ W3) {
  int idx = blockIdx.x * 512 + threadIdx.x;     // 229376 threads total
  if (idx < 131072) {
    int j = idx & 7, lane = (idx >> 3) & 63, vt = (idx >> 9) & 15,
        ut = (idx >> 13) & 7, h = (idx >> 16) & 1;
    int u = ut * 32 + (lane & 31);
    int v = vt * 16 + (lane >> 5) * 8 + j;
    int s = u * 256 + v;
    float ap = 1.f / (1.f + expf(-alp[s]));
    float an = 1.f / (1.f + expf(-aln[s]));
    bool  m  = ap > an;
    float val = h ? (m ? 0.f : -an) : (m ? ap : 0.f);   // neg sign folded
    A3[idx] = f2bf_rne(val);
  } else {
    int k = idx - 131072;                       // 0 .. 98303
    int j = k & 7, lane = (k >> 3) & 63, kt = (k >> 9) & 7,
        ot = (k >> 12) & 3, hw = (k >> 14);     // hw = l*2 + (0=pos,1=neg)
    int o = ot * 32 + (lane & 31);
    int d = kt * 16 + (lane >> 5) * 8 + j;
    const float* src = (hw & 1) ? wn : wp;
    W3[k] = f2bf_rne(src[(hw >> 1) * 16384 + o * 128 + d]);
  }
}

__global__ __launch_bounds__(256, 2) void gnn_kernel(
    const float* __restrict__ X,
    const unsigned short* __restrict__ A3,
    const unsigned short* __restrict__ W3,
    const float* __restrict__ ln_g, const float* __restrict__ ln_b,
    const float* __restrict__ ro_g, const float* __restrict__ ro_b,
    float* __restrict__ out) {
  extern __shared__ char smem[];
  const int tid  = threadIdx.x;
  const int wid  = tid >> 6;        // 0..3: o-slice base = wid*32
  const int lane = tid & 63;
  const int l31  = lane & 31;
  const int hi   = lane >> 5;
  const int b    = blockIdx.x;
  const int gp   = GOFF + wid * 2304;   // private Gc_T: [32 o][72 B rows]

  // ---- stage H = bf16(X[b]) into LDS ----
  {
    const float4* Xb = (const float4*)(X + (size_t)b * 256 * 128);
#pragma unroll 8
    for (int i = 0; i < 32; ++i) {
      int idx = tid + i * 256;
      int v = idx >> 5, d = (idx & 31) * 4;
      float4 f = Xb[idx];
      ushort4 p;
      p.x = f2bf(f.x); p.y = f2bf(f.y); p.z = f2bf(f.z); p.w = f2bf(f.w);
      *(ushort4*)(smem + haddr(v, d)) = p;
    }
  }
  __syncthreads();

  for (int l = 0; l < 3; ++l) {
    f32x16 acc[8];                    // 256u x 32o per wave (128 AGPR)
#pragma unroll
    for (int ut = 0; ut < 8; ++ut)
#pragma unroll
      for (int r = 0; r < 16; ++r) acc[ut][r] = 0.f;

    for (int h = 0; h < 2; ++h) {
      const unsigned short* Wb = W3 + (size_t)(((l * 2 + h) * 4 + wid) * 8) * 512;
      const unsigned short* Ab = A3 + (size_t)h * 65536;

      s16x8 wreg[8];                  // this wave's W o-tile (32 regs)
#pragma unroll
      for (int kt = 0; kt < 8; ++kt)
        wreg[kt] = *(const s16x8*)(Wb + (size_t)kt * 512 + lane * 8);

#pragma unroll 1
      for (int c = 0; c < 8; ++c) {   // v-chunks of 32 nodes; NO barriers
        // ---- GEMM1: g0 = H[c][32v] @ W^T (32x32 tile) ----
        f32x16 g0;
#pragma unroll
        for (int r = 0; r < 16; ++r) g0[r] = 0.f;
        const int v0 = c * 32 + l31;
#pragma unroll
        for (int kt = 0; kt < 8; ++kt) {
          s16x8 ha = *(const s16x8*)(smem + haddr(v0, kt * 16 + hi * 8));
          g0 = MFMA32(ha, wreg[kt], g0);
        }
        // write private Gc_T[o = l31][v]; C/D: reg r -> v=(r&3)+8*(r>>2)+4*hi
#pragma unroll
        for (int rq = 0; rq < 4; ++rq) {
          int vr = rq * 8 + hi * 4;
          ushort4 p;
          p.x = f2bf(g0[rq*4+0]); p.y = f2bf(g0[rq*4+1]);
          p.z = f2bf(g0[rq*4+2]); p.w = f2bf(g0[rq*4+3]);
          *(ushort4*)(smem + gp + l31 * 72 + vr * 2) = p;
        }
        // ---- GEMM2: acc[256u x 32o] += A_h[u, chunk c] @ g (wave-local) ----
#pragma unroll
        for (int kt2 = 0; kt2 < 2; ++kt2) {
          s16x8 bf = *(const s16x8*)(smem + gp + l31 * 72 + (kt2 * 16 + hi * 8) * 2);
#pragma unroll
          for (int ut = 0; ut < 8; ++ut) {     // FULL unroll: acc stays AGPR
            s16x8 a = *(const s16x8*)(Ab + (size_t)(ut * 16 + c * 2 + kt2) * 512 + lane * 8);
            acc[ut] = MFMA32(a, bf, acc[ut]);
          }
        }
      } // chunks
    } // halves  — zero barriers above

    // ---- epilogue: GELU + cross-wave LayerNorm (3 barriers) ----
    const float lgv = ln_g[l * 128 + wid * 32 + l31];
    const float lbv = ln_b[l * 128 + wid * 32 + l31];
    float st1[8], st2[8];
#pragma unroll
    for (int ut = 0; ut < 8; ++ut) {
      st1[ut] = 0.f; st2[ut] = 0.f;
#pragma unroll
      for (int r = 0; r < 16; ++r) {
        float x = gelu_fast(acc[ut][r]);
        acc[ut][r] = x;
        float s1 = x, s2 = x * x;
#pragma unroll
        for (int m = 1; m < 32; m <<= 1) {     // reduce this wave's 32-o slice
          s1 += __shfl_xor(s1, m);
          s2 += __shfl_xor(s2, m);
        }
        if (l31 == r) { st1[ut] = s1; st2[ut] = s2; }
      }
    }
    __syncthreads();                 // bar 1: all GEMM / private-Gc reads done
    if (l31 < 16) {                  // stats[u][wid] float2
      int rr = (l31 & 3) + 8 * ((l31 >> 2) & 3) + 4 * hi;
#pragma unroll
      for (int ut = 0; ut < 8; ++ut) {
        int u = ut * 32 + rr;
        float2 pw; pw.x = st1[ut]; pw.y = st2[ut];
        *(float2*)(smem + GOFF + u * 32 + wid * 8) = pw;
      }
    }
    __syncthreads();                 // bar 2: stats ready
#pragma unroll
    for (int ut = 0; ut < 8; ++ut)   // FULL unroll: acc stays AGPR
#pragma unroll
      for (int r = 0; r < 16; ++r) {
        int u = ut * 32 + (r & 3) + 8 * ((r >> 2) & 3) + 4 * hi;
        float mu = 0.f, rs = 0.f;
        if (l31 == r) {
          f32x4 sa = *(const f32x4*)(smem + GOFF + u * 32);
          f32x4 sb = *(const f32x4*)(smem + GOFF + u * 32 + 16);
          float s1 = sa[0] + sa[2] + sb[0] + sb[2];
          float s2 = sa[1] + sa[3] + sb[1] + sb[3];
          mu = s1 * (1.f / 128.f);
          float var = s2 * (1.f / 128.f) - mu * mu;
          rs = rsqrtf(var + 1e-5f);
        }
        mu = __shfl(mu, (lane & 32) + r);      // broadcast within half-wave
        rs = __shfl(rs, (lane & 32) + r);
        float y = (acc[ut][r] - mu) * rs * lgv + lbv;
        *(unsigned short*)(smem + haddr(u, wid * 32 + l31)) = f2bf(y);
      }
    __syncthreads();                 // bar 3: H' ready for next layer
  } // layers

  // ---- readout: mean over nodes + final LN ----
  {
    int d   = tid & 127;
    int grp = tid >> 7;
    float s = 0.f;
    for (int v = grp * 128; v < grp * 128 + 128; ++v)
      s += bf2f(*(const unsigned short*)(smem + haddr(v, d)));
    float* red = (float*)(smem + GOFF);
    red[grp * 128 + d] = s;
    __syncthreads();
    if (tid < 128) {
      red[256 + tid] = (red[tid] + red[128 + tid]) * (1.f / 256.f);
    }
    __syncthreads();
    if (tid < 64) {
      float a  = red[256 + tid];
      float b2 = red[256 + 64 + tid];
      float s1 = a + b2, s2 = a * a + b2 * b2;
#pragma unroll
      for (int m = 1; m < 64; m <<= 1) {
        s1 += __shfl_xor(s1, m);
        s2 += __shfl_xor(s2, m);
      }
      float mu  = s1 * (1.f / 128.f);
      float var = s2 * (1.f / 128.f) - mu * mu;
      float rs  = rsqrtf(var + 1e-5f);
      out[(size_t)b * 128 + tid]      = (a  - mu) * rs * ro_g[tid]      + ro_b[tid];
      out[(size_t)b * 128 + 64 + tid] = (b2 - mu) * rs * ro_g[64 + tid] + ro_b[64 + tid];
    }
  }
}

extern "C" void kernel_launch(void* const* d_in, const int* in_sizes, int n_in,
                              void* d_out, int out_size, void* d_ws, size_t ws_size,
                              hipStream_t stream) {
  const float* X   = (const float*)d_in[0];
  const float* alp = (const float*)d_in[1];
  const float* aln = (const float*)d_in[2];
  const float* wp  = (const float*)d_in[3];
  const float* wn  = (const float*)d_in[4];
  const float* lng = (const float*)d_in[5];
  const float* lnb = (const float*)d_in[6];
  const float* rog = (const float*)d_in[7];
  const float* rob = (const float*)d_in[8];
  float* out = (float*)d_out;

  unsigned short* A3 = (unsigned short*)d_ws;          // 131072 bf16 = 256 KB
  unsigned short* W3 = A3 + 131072;                    //  98304 bf16 = 192 KB

  (void)hipFuncSetAttribute(reinterpret_cast<const void*>(gnn_kernel),
                            hipFuncAttributeMaxDynamicSharedMemorySize, 74752);

  prep_kernel<<<448, 512, 0, stream>>>(alp, aln, wp, wn, A3, W3);
  gnn_kernel<<<2048, 256, 74752, stream>>>(X, A3, W3, lng, lnb, rog, rob, out);
}

// Round 23
// 676.526 us; speedup vs baseline: 12.4345x; 6.7378x over previous
//
#include <hip/hip_runtime.h>
#include <math.h>

// HeterogeneousGNN fused kernel for MI355X (gfx950) — round 23.
// Base = R19/R20 (632 us best). R21/R22's zero-barrier structure is register-
// infeasible (acc[8]+window > file, 3.9GB spill) — abandoned. R19 re-audit:
// spill is phase-boundary only (~2us); dominant cost = latency exposure at
// 2 waves/SIMD, longest chain = GEMM1's 8 serially-dependent MFMAs.
// R23 = R19 + GEMM1 accumulator split into two independent chains (g0: kt
// 0-3, g1: kt 4-7; merged with 16 adds BEFORE the barrier -- nothing extra
// lives across it, unlike R18). Chain depth 8 -> 4.

typedef float  f32x4  __attribute__((ext_vector_type(4)));
typedef float  f32x16 __attribute__((ext_vector_type(16)));
typedef short  s16x8  __attribute__((ext_vector_type(8)));
typedef __bf16 bf16x8 __attribute__((ext_vector_type(8)));

#define GOFF 65536   // Gc region byte offset (10240 B)

// LDS-only barrier: commits LDS ops, leaves global loads in flight (R20).
#define LDS_BARRIER() asm volatile("s_waitcnt lgkmcnt(0)\n\ts_barrier" ::: "memory")

__device__ __forceinline__ unsigned short f2bf(float f) {
  __bf16 h = (__bf16)f;
  return __builtin_bit_cast(unsigned short, h);
}
__device__ __forceinline__ float bf2f(unsigned short h) {
  return __builtin_bit_cast(float, (unsigned int)h << 16);
}
__device__ __forceinline__ unsigned short f2bf_rne(float f) {
  unsigned int u = __builtin_bit_cast(unsigned int, f);
  u = (u + 0x7fffu + ((u >> 16) & 1u)) >> 16;
  return (unsigned short)u;
}

// exact-GELU via A&S 7.1.26 erf (max abs err 1.5e-7, << bf16 rounding)
__device__ __forceinline__ float gelu_fast(float x) {
  float z = fabsf(x) * 0.70710678f;
  float t = __builtin_amdgcn_rcpf(1.f + 0.3275911f * z);
  float p = t * (0.254829592f + t * (-0.284496736f + t * (1.421413741f +
            t * (-1.453152027f + t * 1.061405429f))));
  float e = __builtin_expf(-z * z);
  float erfv = 1.f - p * e;
  erfv = (x < 0.f) ? -erfv : erfv;
  return 0.5f * x * (1.f + erfv);
}

// H: [256 v][128 d] bf16; XOR (v&15) -> column b128 reads 2-way (free).
__device__ __forceinline__ int haddr(int v, int d) {
  return v * 256 + ((d * 2) ^ ((v & 15) << 4));
}
// Gc^T: [128 o][32 v] bf16, 80-B row stride; slot(o)=5*o mod 8 -> 4-way floor.
__device__ __forceinline__ int gaddr(int o, int vr) {
  return GOFF + o * 80 + vr * 2;
}

#define MFMA32(a, b, c) __builtin_amdgcn_mfma_f32_32x32x16_bf16( \
    __builtin_bit_cast(bf16x8, (a)), __builtin_bit_cast(bf16x8, (b)), (c), 0, 0, 0)

// ---- prep: fragment-ordered A3 / W3 (bf16) ----
// A3[h][ut 0..7][vt 0..15][lane][j] = Ac_h[u=ut*32+(lane&31)][v=vt*16+(lane>>5)*8+j]
// W3[hw 0..5][ot 0..3][kt 0..7][lane][j] = W_hw[o=ot*32+(lane&31)][d=kt*16+(lane>>5)*8+j]
__global__ void prep_kernel(const float* __restrict__ alp, const float* __restrict__ aln,
                            const float* __restrict__ wp,  const float* __restrict__ wn,
                            unsigned short* __restrict__ A3, unsigned short* __restrict__ W3) {
  int idx = blockIdx.x * 512 + threadIdx.x;     // 229376 threads total
  if (idx < 131072) {
    int j = idx & 7, lane = (idx >> 3) & 63, vt = (idx >> 9) & 15,
        ut = (idx >> 13) & 7, h = (idx >> 16) & 1;
    int u = ut * 32 + (lane & 31);
    int v = vt * 16 + (lane >> 5) * 8 + j;
    int s = u * 256 + v;
    float ap = 1.f / (1.f + expf(-alp[s]));
    float an = 1.f / (1.f + expf(-aln[s]));
    bool  m  = ap > an;
    float val = h ? (m ? 0.f : -an) : (m ? ap : 0.f);   // neg sign folded
    A3[idx] = f2bf_rne(val);
  } else {
    int k = idx - 131072;                       // 0 .. 98303
    int j = k & 7, lane = (k >> 3) & 63, kt = (k >> 9) & 7,
        ot = (k >> 12) & 3, hw = (k >> 14);     // hw = l*2 + (0=pos,1=neg)
    int o = ot * 32 + (lane & 31);
    int d = kt * 16 + (lane >> 5) * 8 + j;
    const float* src = (hw & 1) ? wn : wp;
    W3[k] = f2bf_rne(src[(hw >> 1) * 16384 + o * 128 + d]);
  }
}

__global__ __launch_bounds__(256, 2) void gnn_kernel(
    const float* __restrict__ X,
    const unsigned short* __restrict__ A3,
    const unsigned short* __restrict__ W3,
    const float* __restrict__ ln_g, const float* __restrict__ ln_b,
    const float* __restrict__ ro_g, const float* __restrict__ ro_b,
    float* __restrict__ out) {
  extern __shared__ char smem[];
  const int tid  = threadIdx.x;
  const int wid  = tid >> 6;        // 0..3
  const int lane = tid & 63;
  const int l31  = lane & 31;
  const int hi   = lane >> 5;
  const int b    = blockIdx.x;

  // ---- stage H = bf16(X[b]) into LDS ----
  {
    const float4* Xb = (const float4*)(X + (size_t)b * 256 * 128);
#pragma unroll 8
    for (int i = 0; i < 32; ++i) {
      int idx = tid + i * 256;                 // 8192 float4 chunks
      int v = idx >> 5, d = (idx & 31) * 4;
      float4 f = Xb[idx];
      ushort4 p;
      p.x = f2bf(f.x); p.y = f2bf(f.y); p.z = f2bf(f.z); p.w = f2bf(f.w);
      *(ushort4*)(smem + haddr(v, d)) = p;
    }
  }
  __syncthreads();

  f32x16 acc[2][4];                  // wave tile: u = wid*64..+64, o = 0..128
  for (int l = 0; l < 3; ++l) {
#pragma unroll
    for (int mt = 0; mt < 2; ++mt)
#pragma unroll
      for (int nt = 0; nt < 4; ++nt)
#pragma unroll
        for (int r = 0; r < 16; ++r) acc[mt][nt][r] = 0.f;

    for (int h = 0; h < 2; ++h) {
      const unsigned short* Wb = W3 + (size_t)(((l * 2 + h) * 4 + wid) * 8) * 512;
      const unsigned short* Ab = A3 + (size_t)((h * 8 + wid * 2) * 16) * 512;

      // hoisted W o-tile fragments, reused by all 8 chunks
      s16x8 wreg[8];
#pragma unroll
      for (int kt = 0; kt < 8; ++kt)
        wreg[kt] = *(const s16x8*)(Wb + (size_t)kt * 512 + lane * 8);

      for (int c = 0; c < 8; ++c) {            // v-chunks of 32 nodes
        // prefetch this chunk's A fragments (consumed after the barriers)
        s16x8 pa[4];
#pragma unroll
        for (int kt = 0; kt < 2; ++kt) {
          pa[kt * 2 + 0] = *(const s16x8*)(Ab + (size_t)(0 * 16 + c * 2 + kt) * 512 + lane * 8);
          pa[kt * 2 + 1] = *(const s16x8*)(Ab + (size_t)(1 * 16 + c * 2 + kt) * 512 + lane * 8);
        }

        // ---- GEMM1: Gc[32v][128o] = H[c] @ W^T; TWO independent chains ----
        f32x16 g0, g1;
#pragma unroll
        for (int r = 0; r < 16; ++r) { g0[r] = 0.f; g1[r] = 0.f; }
        const int v0 = c * 32 + l31;
#pragma unroll
        for (int kt = 0; kt < 4; ++kt) {       // K = d = 128, split 4+4
          s16x8 ha = *(const s16x8*)(smem + haddr(v0, kt * 16 + hi * 8));
          s16x8 hb = *(const s16x8*)(smem + haddr(v0, (kt + 4) * 16 + hi * 8));
          g0 = MFMA32(ha, wreg[kt], g0);
          g1 = MFMA32(hb, wreg[kt + 4], g1);
        }
#pragma unroll
        for (int r = 0; r < 16; ++r) g0[r] += g1[r];   // merge BEFORE barrier
        LDS_BARRIER();                         // prev chunk's GEMM2 reads done
        {
          const int og = wid * 32 + l31;       // C/D col = lane&31
#pragma unroll
          for (int rq = 0; rq < 4; ++rq) {     // rows v = (r&3)+8*(r>>2)+4*hi
            int vr = rq * 8 + hi * 4;
            ushort4 p;
            p.x = f2bf(g0[rq*4+0]); p.y = f2bf(g0[rq*4+1]);
            p.z = f2bf(g0[rq*4+2]); p.w = f2bf(g0[rq*4+3]);
            *(ushort4*)(smem + gaddr(og, vr)) = p;
          }
        }
        LDS_BARRIER();                         // Gc ready (writes committed)

        // ---- GEMM2: acc += Ac_h[u, 32c..] @ Gc; 64u x 128o per wave ----
#pragma unroll
        for (int kt = 0; kt < 2; ++kt) {       // K = v-chunk = 32
#pragma unroll
          for (int nt = 0; nt < 4; ++nt) {
            s16x8 bf = *(const s16x8*)(smem + gaddr(nt * 32 + l31, kt * 16 + hi * 8));
            acc[0][nt] = MFMA32(pa[kt * 2 + 0], bf, acc[0][nt]);
            acc[1][nt] = MFMA32(pa[kt * 2 + 1], bf, acc[1][nt]);
          }
        }
      } // chunks
    } // halves

    // ---- epilogue: fast exact-GELU + wave-local LayerNorm -> H ----
    {
      float lg[4], lb[4];
#pragma unroll
      for (int nt = 0; nt < 4; ++nt) {
        lg[nt] = ln_g[l * 128 + nt * 32 + l31];
        lb[nt] = ln_b[l * 128 + nt * 32 + l31];
      }
#pragma unroll
      for (int mt = 0; mt < 2; ++mt)
#pragma unroll
        for (int r = 0; r < 16; ++r) {
          float x0 = gelu_fast(acc[mt][0][r]);
          float x1 = gelu_fast(acc[mt][1][r]);
          float x2 = gelu_fast(acc[mt][2][r]);
          float x3 = gelu_fast(acc[mt][3][r]);
          acc[mt][0][r] = x0; acc[mt][1][r] = x1;
          acc[mt][2][r] = x2; acc[mt][3][r] = x3;
          float s1 = x0 + x1 + x2 + x3;
          float s2 = x0 * x0 + x1 * x1 + x2 * x2 + x3 * x3;
#pragma unroll
          for (int m = 1; m < 32; m <<= 1) {   // full row (128 cols) reduce
            s1 += __shfl_xor(s1, m);
            s2 += __shfl_xor(s2, m);
          }
          float mu  = s1 * (1.f / 128.f);
          float var = s2 * (1.f / 128.f) - mu * mu;
          float rs  = rsqrtf(var + 1e-5f);
          int u = wid * 64 + mt * 32 + (r & 3) + 8 * ((r >> 2) & 3) + 4 * hi;
#pragma unroll
          for (int nt = 0; nt < 4; ++nt) {
            float y = (acc[mt][nt][r] - mu) * rs * lg[nt] + lb[nt];
            *(unsigned short*)(smem + haddr(u, nt * 32 + l31)) = f2bf(y);
          }
        }
    }
    __syncthreads();                           // H' ready for next layer
  } // layers

  // ---- readout: mean over nodes + final LN ----
  {
    int d   = tid & 127;
    int grp = tid >> 7;                        // 0..1, 128 rows each
    float s = 0.f;
    for (int v = grp * 128; v < grp * 128 + 128; ++v)
      s += bf2f(*(const unsigned short*)(smem + haddr(v, d)));
    float* red = (float*)(smem + GOFF);        // Gc region is dead now
    red[grp * 128 + d] = s;
    __syncthreads();
    if (tid < 128) {
      red[256 + tid] = (red[tid] + red[128 + tid]) * (1.f / 256.f);
    }
    __syncthreads();
    if (tid < 64) {
      float a  = red[256 + tid];
      float b2 = red[256 + 64 + tid];
      float s1 = a + b2, s2 = a * a + b2 * b2;
#pragma unroll
      for (int m = 1; m < 64; m <<= 1) {
        s1 += __shfl_xor(s1, m);
        s2 += __shfl_xor(s2, m);
      }
      float mu  = s1 * (1.f / 128.f);
      float var = s2 * (1.f / 128.f) - mu * mu;
      float rs  = rsqrtf(var + 1e-5f);
      out[(size_t)b * 128 + tid]      = (a  - mu) * rs * ro_g[tid]      + ro_b[tid];
      out[(size_t)b * 128 + 64 + tid] = (b2 - mu) * rs * ro_g[64 + tid] + ro_b[64 + tid];
    }
  }
}

extern "C" void kernel_launch(void* const* d_in, const int* in_sizes, int n_in,
                              void* d_out, int out_size, void* d_ws, size_t ws_size,
                              hipStream_t stream) {
  const float* X   = (const float*)d_in[0];
  const float* alp = (const float*)d_in[1];
  const float* aln = (const float*)d_in[2];
  const float* wp  = (const float*)d_in[3];
  const float* wn  = (const float*)d_in[4];
  const float* lng = (const float*)d_in[5];
  const float* lnb = (const float*)d_in[6];
  const float* rog = (const float*)d_in[7];
  const float* rob = (const float*)d_in[8];
  float* out = (float*)d_out;

  unsigned short* A3 = (unsigned short*)d_ws;          // 131072 bf16 = 256 KB
  unsigned short* W3 = A3 + 131072;                    //  98304 bf16 = 192 KB

  (void)hipFuncSetAttribute(reinterpret_cast<const void*>(gnn_kernel),
                            hipFuncAttributeMaxDynamicSharedMemorySize, 75776);

  prep_kernel<<<448, 512, 0, stream>>>(alp, aln, wp, wn, A3, W3);
  gnn_kernel<<<2048, 256, 75776, stream>>>(X, A3, W3, lng, lnb, rog, rob, out);
}

// Round 24
// 630.377 us; speedup vs baseline: 13.3448x; 1.0732x over previous
//
#include <hip/hip_runtime.h>
#include <math.h>

// HeterogeneousGNN fused kernel for MI355X (gfx950) — round 24.
// Base = R19/R20 (632 us best). R23's chain-split reverted (+16 regs -> more
// spill than ILP gain). R24 = R19/R20 + T5: s_setprio(1) around the MFMA
// clusters. Regime check: 2 independent blocks/CU drift out of phase (no
// inter-block sync) -> CU scheduler can favor the MFMA-entering wave over
// the other block's staging waves (m191: +4-7% in this regime). Zero
// register / LDS / barrier change.

typedef float  f32x4  __attribute__((ext_vector_type(4)));
typedef float  f32x16 __attribute__((ext_vector_type(16)));
typedef short  s16x8  __attribute__((ext_vector_type(8)));
typedef __bf16 bf16x8 __attribute__((ext_vector_type(8)));

#define GOFF 65536   // Gc region byte offset (10240 B)

// LDS-only barrier: commits LDS ops, leaves global loads in flight (R20).
#define LDS_BARRIER() asm volatile("s_waitcnt lgkmcnt(0)\n\ts_barrier" ::: "memory")

__device__ __forceinline__ unsigned short f2bf(float f) {
  __bf16 h = (__bf16)f;
  return __builtin_bit_cast(unsigned short, h);
}
__device__ __forceinline__ float bf2f(unsigned short h) {
  return __builtin_bit_cast(float, (unsigned int)h << 16);
}
__device__ __forceinline__ unsigned short f2bf_rne(float f) {
  unsigned int u = __builtin_bit_cast(unsigned int, f);
  u = (u + 0x7fffu + ((u >> 16) & 1u)) >> 16;
  return (unsigned short)u;
}

// exact-GELU via A&S 7.1.26 erf (max abs err 1.5e-7, << bf16 rounding)
__device__ __forceinline__ float gelu_fast(float x) {
  float z = fabsf(x) * 0.70710678f;
  float t = __builtin_amdgcn_rcpf(1.f + 0.3275911f * z);
  float p = t * (0.254829592f + t * (-0.284496736f + t * (1.421413741f +
            t * (-1.453152027f + t * 1.061405429f))));
  float e = __builtin_expf(-z * z);
  float erfv = 1.f - p * e;
  erfv = (x < 0.f) ? -erfv : erfv;
  return 0.5f * x * (1.f + erfv);
}

// H: [256 v][128 d] bf16; XOR (v&15) -> column b128 reads 2-way (free).
__device__ __forceinline__ int haddr(int v, int d) {
  return v * 256 + ((d * 2) ^ ((v & 15) << 4));
}
// Gc^T: [128 o][32 v] bf16, 80-B row stride; slot(o)=5*o mod 8 -> 4-way floor.
__device__ __forceinline__ int gaddr(int o, int vr) {
  return GOFF + o * 80 + vr * 2;
}

#define MFMA32(a, b, c) __builtin_amdgcn_mfma_f32_32x32x16_bf16( \
    __builtin_bit_cast(bf16x8, (a)), __builtin_bit_cast(bf16x8, (b)), (c), 0, 0, 0)

// ---- prep: fragment-ordered A3 / W3 (bf16) ----
// A3[h][ut 0..7][vt 0..15][lane][j] = Ac_h[u=ut*32+(lane&31)][v=vt*16+(lane>>5)*8+j]
// W3[hw 0..5][ot 0..3][kt 0..7][lane][j] = W_hw[o=ot*32+(lane&31)][d=kt*16+(lane>>5)*8+j]
__global__ void prep_kernel(const float* __restrict__ alp, const float* __restrict__ aln,
                            const float* __restrict__ wp,  const float* __restrict__ wn,
                            unsigned short* __restrict__ A3, unsigned short* __restrict__ W3) {
  int idx = blockIdx.x * 512 + threadIdx.x;     // 229376 threads total
  if (idx < 131072) {
    int j = idx & 7, lane = (idx >> 3) & 63, vt = (idx >> 9) & 15,
        ut = (idx >> 13) & 7, h = (idx >> 16) & 1;
    int u = ut * 32 + (lane & 31);
    int v = vt * 16 + (lane >> 5) * 8 + j;
    int s = u * 256 + v;
    float ap = 1.f / (1.f + expf(-alp[s]));
    float an = 1.f / (1.f + expf(-aln[s]));
    bool  m  = ap > an;
    float val = h ? (m ? 0.f : -an) : (m ? ap : 0.f);   // neg sign folded
    A3[idx] = f2bf_rne(val);
  } else {
    int k = idx - 131072;                       // 0 .. 98303
    int j = k & 7, lane = (k >> 3) & 63, kt = (k >> 9) & 7,
        ot = (k >> 12) & 3, hw = (k >> 14);     // hw = l*2 + (0=pos,1=neg)
    int o = ot * 32 + (lane & 31);
    int d = kt * 16 + (lane >> 5) * 8 + j;
    const float* src = (hw & 1) ? wn : wp;
    W3[k] = f2bf_rne(src[(hw >> 1) * 16384 + o * 128 + d]);
  }
}

__global__ __launch_bounds__(256, 2) void gnn_kernel(
    const float* __restrict__ X,
    const unsigned short* __restrict__ A3,
    const unsigned short* __restrict__ W3,
    const float* __restrict__ ln_g, const float* __restrict__ ln_b,
    const float* __restrict__ ro_g, const float* __restrict__ ro_b,
    float* __restrict__ out) {
  extern __shared__ char smem[];
  const int tid  = threadIdx.x;
  const int wid  = tid >> 6;        // 0..3
  const int lane = tid & 63;
  const int l31  = lane & 31;
  const int hi   = lane >> 5;
  const int b    = blockIdx.x;

  // ---- stage H = bf16(X[b]) into LDS ----
  {
    const float4* Xb = (const float4*)(X + (size_t)b * 256 * 128);
#pragma unroll 8
    for (int i = 0; i < 32; ++i) {
      int idx = tid + i * 256;                 // 8192 float4 chunks
      int v = idx >> 5, d = (idx & 31) * 4;
      float4 f = Xb[idx];
      ushort4 p;
      p.x = f2bf(f.x); p.y = f2bf(f.y); p.z = f2bf(f.z); p.w = f2bf(f.w);
      *(ushort4*)(smem + haddr(v, d)) = p;
    }
  }
  __syncthreads();

  f32x16 acc[2][4];                  // wave tile: u = wid*64..+64, o = 0..128
  for (int l = 0; l < 3; ++l) {
#pragma unroll
    for (int mt = 0; mt < 2; ++mt)
#pragma unroll
      for (int nt = 0; nt < 4; ++nt)
#pragma unroll
        for (int r = 0; r < 16; ++r) acc[mt][nt][r] = 0.f;

    for (int h = 0; h < 2; ++h) {
      const unsigned short* Wb = W3 + (size_t)(((l * 2 + h) * 4 + wid) * 8) * 512;
      const unsigned short* Ab = A3 + (size_t)((h * 8 + wid * 2) * 16) * 512;

      // hoisted W o-tile fragments, reused by all 8 chunks
      s16x8 wreg[8];
#pragma unroll
      for (int kt = 0; kt < 8; ++kt)
        wreg[kt] = *(const s16x8*)(Wb + (size_t)kt * 512 + lane * 8);

      for (int c = 0; c < 8; ++c) {            // v-chunks of 32 nodes
        // prefetch this chunk's A fragments (consumed after the barriers)
        s16x8 pa[4];
#pragma unroll
        for (int kt = 0; kt < 2; ++kt) {
          pa[kt * 2 + 0] = *(const s16x8*)(Ab + (size_t)(0 * 16 + c * 2 + kt) * 512 + lane * 8);
          pa[kt * 2 + 1] = *(const s16x8*)(Ab + (size_t)(1 * 16 + c * 2 + kt) * 512 + lane * 8);
        }

        // ---- GEMM1: Gc[32v][128o] = H[c] @ W^T; one 32x32 tile per wave ----
        f32x16 g0;
#pragma unroll
        for (int r = 0; r < 16; ++r) g0[r] = 0.f;
        const int v0 = c * 32 + l31;
        __builtin_amdgcn_s_setprio(1);
#pragma unroll
        for (int kt = 0; kt < 8; ++kt) {       // K = d = 128
          s16x8 ha = *(const s16x8*)(smem + haddr(v0, kt * 16 + hi * 8));
          g0 = MFMA32(ha, wreg[kt], g0);
        }
        __builtin_amdgcn_s_setprio(0);
        LDS_BARRIER();                         // prev chunk's GEMM2 reads done
        {
          const int og = wid * 32 + l31;       // C/D col = lane&31
#pragma unroll
          for (int rq = 0; rq < 4; ++rq) {     // rows v = (r&3)+8*(r>>2)+4*hi
            int vr = rq * 8 + hi * 4;
            ushort4 p;
            p.x = f2bf(g0[rq*4+0]); p.y = f2bf(g0[rq*4+1]);
            p.z = f2bf(g0[rq*4+2]); p.w = f2bf(g0[rq*4+3]);
            *(ushort4*)(smem + gaddr(og, vr)) = p;
          }
        }
        LDS_BARRIER();                         // Gc ready (writes committed)

        // ---- GEMM2: acc += Ac_h[u, 32c..] @ Gc; 64u x 128o per wave ----
        __builtin_amdgcn_s_setprio(1);
#pragma unroll
        for (int kt = 0; kt < 2; ++kt) {       // K = v-chunk = 32
#pragma unroll
          for (int nt = 0; nt < 4; ++nt) {
            s16x8 bf = *(const s16x8*)(smem + gaddr(nt * 32 + l31, kt * 16 + hi * 8));
            acc[0][nt] = MFMA32(pa[kt * 2 + 0], bf, acc[0][nt]);
            acc[1][nt] = MFMA32(pa[kt * 2 + 1], bf, acc[1][nt]);
          }
        }
        __builtin_amdgcn_s_setprio(0);
      } // chunks
    } // halves

    // ---- epilogue: fast exact-GELU + wave-local LayerNorm -> H ----
    {
      float lg[4], lb[4];
#pragma unroll
      for (int nt = 0; nt < 4; ++nt) {
        lg[nt] = ln_g[l * 128 + nt * 32 + l31];
        lb[nt] = ln_b[l * 128 + nt * 32 + l31];
      }
#pragma unroll
      for (int mt = 0; mt < 2; ++mt)
#pragma unroll
        for (int r = 0; r < 16; ++r) {
          float x0 = gelu_fast(acc[mt][0][r]);
          float x1 = gelu_fast(acc[mt][1][r]);
          float x2 = gelu_fast(acc[mt][2][r]);
          float x3 = gelu_fast(acc[mt][3][r]);
          acc[mt][0][r] = x0; acc[mt][1][r] = x1;
          acc[mt][2][r] = x2; acc[mt][3][r] = x3;
          float s1 = x0 + x1 + x2 + x3;
          float s2 = x0 * x0 + x1 * x1 + x2 * x2 + x3 * x3;
#pragma unroll
          for (int m = 1; m < 32; m <<= 1) {   // full row (128 cols) reduce
            s1 += __shfl_xor(s1, m);
            s2 += __shfl_xor(s2, m);
          }
          float mu  = s1 * (1.f / 128.f);
          float var = s2 * (1.f / 128.f) - mu * mu;
          float rs  = rsqrtf(var + 1e-5f);
          int u = wid * 64 + mt * 32 + (r & 3) + 8 * ((r >> 2) & 3) + 4 * hi;
#pragma unroll
          for (int nt = 0; nt < 4; ++nt) {
            float y = (acc[mt][nt][r] - mu) * rs * lg[nt] + lb[nt];
            *(unsigned short*)(smem + haddr(u, nt * 32 + l31)) = f2bf(y);
          }
        }
    }
    __syncthreads();                           // H' ready for next layer
  } // layers

  // ---- readout: mean over nodes + final LN ----
  {
    int d   = tid & 127;
    int grp = tid >> 7;                        // 0..1, 128 rows each
    float s = 0.f;
    for (int v = grp * 128; v < grp * 128 + 128; ++v)
      s += bf2f(*(const unsigned short*)(smem + haddr(v, d)));
    float* red = (float*)(smem + GOFF);        // Gc region is dead now
    red[grp * 128 + d] = s;
    __syncthreads();
    if (tid < 128) {
      red[256 + tid] = (red[tid] + red[128 + tid]) * (1.f / 256.f);
    }
    __syncthreads();
    if (tid < 64) {
      float a  = red[256 + tid];
      float b2 = red[256 + 64 + tid];
      float s1 = a + b2, s2 = a * a + b2 * b2;
#pragma unroll
      for (int m = 1; m < 64; m <<= 1) {
        s1 += __shfl_xor(s1, m);
        s2 += __shfl_xor(s2, m);
      }
      float mu  = s1 * (1.f / 128.f);
      float var = s2 * (1.f / 128.f) - mu * mu;
      float rs  = rsqrtf(var + 1e-5f);
      out[(size_t)b * 128 + tid]      = (a  - mu) * rs * ro_g[tid]      + ro_b[tid];
      out[(size_t)b * 128 + 64 + tid] = (b2 - mu) * rs * ro_g[64 + tid] + ro_b[64 + tid];
    }
  }
}

extern "C" void kernel_launch(void* const* d_in, const int* in_sizes, int n_in,
                              void* d_out, int out_size, void* d_ws, size_t ws_size,
                              hipStream_t stream) {
  const float* X   = (const float*)d_in[0];
  const float* alp = (const float*)d_in[1];
  const float* aln = (const float*)d_in[2];
  const float* wp  = (const float*)d_in[3];
  const float* wn  = (const float*)d_in[4];
  const float* lng = (const float*)d_in[5];
  const float* lnb = (const float*)d_in[6];
  const float* rog = (const float*)d_in[7];
  const float* rob = (const float*)d_in[8];
  float* out = (float*)d_out;

  unsigned short* A3 = (unsigned short*)d_ws;          // 131072 bf16 = 256 KB
  unsigned short* W3 = A3 + 131072;                    //  98304 bf16 = 192 KB

  (void)hipFuncSetAttribute(reinterpret_cast<const void*>(gnn_kernel),
                            hipFuncAttributeMaxDynamicSharedMemorySize, 75776);

  prep_kernel<<<448, 512, 0, stream>>>(alp, aln, wp, wn, A3, W3);
  gnn_kernel<<<2048, 256, 75776, stream>>>(X, A3, W3, lng, lnb, rog, rob, out);
}